// Round 2
// baseline (495.676 us; speedup 1.0000x reference)
//
#include <hip/hip_runtime.h>
#include <math.h>

// Tile: 256 (x) x 32 (y) outputs per 256-thread block.
// Each thread: 4 output cols (float4) x 8 output rows, accumulated in registers.
// tx = tid & 63 --> a wave's 64 lanes all share the same y-strip, so every
// ds_read_b128 has all lanes on the SAME in_tile row (stride-16B pattern,
// 2-way bank aliasing only = free). No h-arrays in LDS at all.
#define TILE_X 256
#define TILE_Y 32
#define IN_W (TILE_X + 8)   // 264 floats/row (x-halo 4 each side, float4 aligned)
#define IN_H (TILE_Y + 6)   // 38 rows (y-halo 3 each side)
#define NCHUNK (IN_W / 4)   // 66 float4 chunks per row

struct GaussCoefs {
    float g3[3];
    float g5[5];
    float g7[7];
};

__global__ __launch_bounds__(256, 4) void mgdf_kernel(
    const float* __restrict__ s,
    const float* __restrict__ w1p, const float* __restrict__ w2p,
    const float* __restrict__ w3p, const float* __restrict__ w4p,
    float* __restrict__ out,
    GaussCoefs gc)
{
    __shared__ float in_tile[IN_H][IN_W];

    const int tid = threadIdx.x;
    const int plane = blockIdx.z;          // b*C + c
    const int x0 = blockIdx.x * TILE_X;
    const int y0 = blockIdx.y * TILE_Y;
    const int Wd = 512, Hd = 512;
    const float* sp = s + (size_t)plane * (Hd * Wd);

    // Fold the diff chain:
    // w1*s + w2*(s-s3) + w3*(s3-s5) + w4*(s5-s7)
    //   = (w1+w2)*s + (w3-w2)*s3 + (w4-w3)*s5 + (-w4)*s7
    const float w1 = *w1p, w2 = *w2p, w3 = *w3p, w4 = *w4p;
    const float a0 = w1 + w2;
    const float a3 = w3 - w2;
    const float a5 = w4 - w3;
    const float a7 = -w4;

    // Precombined vertical coefficients (uniform scalars).
    float cv3[3], cv5[5], cv7[7];
#pragma unroll
    for (int t = 0; t < 3; ++t) cv3[t] = a3 * gc.g3[t];
#pragma unroll
    for (int t = 0; t < 5; ++t) cv5[t] = a5 * gc.g5[t];
#pragma unroll
    for (int t = 0; t < 7; ++t) cv7[t] = a7 * gc.g7[t];

    // ---- Stage input tile (zero-padded at image borders) ----
    for (int c = tid; c < IN_H * NCHUNK; c += 256) {
        const int r  = c / NCHUNK;
        const int c4 = c % NCHUNK;
        const int gy = y0 - 3 + r;
        const int gx = x0 - 4 + c4 * 4;
        float4 v = make_float4(0.f, 0.f, 0.f, 0.f);
        if (gy >= 0 && gy < Hd) {
            const float* rowp = sp + (size_t)gy * Wd;
            if (gx >= 0 && gx + 3 < Wd) {
                v = *(const float4*)(rowp + gx);
            } else {
                float tmp[4];
#pragma unroll
                for (int j = 0; j < 4; ++j) {
                    const int x = gx + j;
                    tmp[j] = (x >= 0 && x < Wd) ? rowp[x] : 0.f;
                }
                v = make_float4(tmp[0], tmp[1], tmp[2], tmp[3]);
            }
        }
        *(float4*)&in_tile[r][c4 * 4] = v;
    }
    __syncthreads();

    // ---- Per-thread strip: 4 cols x 8 rows ----
    const int tx = tid & 63;       // 64 chunks across 256 cols
    const int ystrip = tid >> 2;   // placeholder, fixed below
    // NOTE: must be tid >> 6 so a wave shares one strip:
    const int ys = tid >> 6;       // 4 strips of 8 rows
    (void)ystrip;
    const int xb = tx * 4;         // in_tile col base (== output tile col base)
    const int row0 = ys * 8;       // output tile row base; in_tile rows row0..row0+13

    float acc[8][4];
#pragma unroll
    for (int j = 0; j < 8; ++j)
#pragma unroll
        for (int c = 0; c < 4; ++c) acc[j][c] = 0.f;

#pragma unroll
    for (int i = 0; i < 14; ++i) {
        const float* rp = &in_tile[row0 + i][xb];
        const float4 A = *(const float4*)(rp);
        const float4 Bv = *(const float4*)(rp + 4);
        const float4 Cv = *(const float4*)(rp + 8);
        const float v[12] = {A.x, A.y, A.z, A.w,
                             Bv.x, Bv.y, Bv.z, Bv.w,
                             Cv.x, Cv.y, Cv.z, Cv.w};

        // Horizontal convs for this input row (output col o needs v[o+1..o+7]).
        float h7r[4], h5r[4], h3r[4];
#pragma unroll
        for (int c = 0; c < 4; ++c) {
            float h = 0.f;
#pragma unroll
            for (int t = 0; t < 7; ++t) h = fmaf(gc.g7[t], v[c + 1 + t], h);
            h7r[c] = h;
        }
        if (i >= 1 && i <= 12) {
#pragma unroll
            for (int c = 0; c < 4; ++c) {
                float h = 0.f;
#pragma unroll
                for (int t = 0; t < 5; ++t) h = fmaf(gc.g5[t], v[c + 2 + t], h);
                h5r[c] = h;
            }
        }
        if (i >= 2 && i <= 11) {
#pragma unroll
            for (int c = 0; c < 4; ++c) {
                float h = 0.f;
#pragma unroll
                for (int t = 0; t < 3; ++t) h = fmaf(gc.g3[t], v[c + 3 + t], h);
                h3r[c] = h;
            }
        }

        // Scatter-accumulate into the output rows that use this input row.
        // Output row j uses input row i with vertical offset d = i - j:
        //   g7[d] (d in 0..6), g5[d-1] (d in 1..5), g3[d-2] (d in 2..4), s (d==3).
#pragma unroll
        for (int d = 0; d < 7; ++d) {
            const int j = i - d;
            if (j < 0 || j > 7) continue;
#pragma unroll
            for (int c = 0; c < 4; ++c) {
                float t = acc[j][c];
                t = fmaf(cv7[d], h7r[c], t);
                if (d >= 1 && d <= 5) t = fmaf(cv5[d - 1], h5r[c], t);
                if (d >= 2 && d <= 4) t = fmaf(cv3[d - 2], h3r[c], t);
                acc[j][c] = t;
            }
        }
        if (i >= 3 && i <= 10) {
            const int j = i - 3;
#pragma unroll
            for (int c = 0; c < 4; ++c)
                acc[j][c] = fmaf(a0, v[4 + c], acc[j][c]);
        }
    }

    // ---- Store 8 float4 rows ----
    float* outp = out + (size_t)plane * (Hd * Wd) + (size_t)(y0 + row0) * Wd + x0 + xb;
#pragma unroll
    for (int j = 0; j < 8; ++j) {
        *(float4*)(outp + (size_t)j * Wd) =
            make_float4(acc[j][0], acc[j][1], acc[j][2], acc[j][3]);
    }
}

static void fill_gauss(float* g, int k) {
    const double sigma = 0.3 * ((k - 1) * 0.5 - 1.0) + 0.8;
    double t[7], sum = 0.0;
    for (int i = 0; i < k; ++i) {
        const double x = (double)(i - k / 2);
        t[i] = exp(-x * x / (2.0 * sigma * sigma));
        sum += t[i];
    }
    for (int i = 0; i < k; ++i) g[i] = (float)(t[i] / sum);
}

extern "C" void kernel_launch(void* const* d_in, const int* in_sizes, int n_in,
                              void* d_out, int out_size, void* d_ws, size_t ws_size,
                              hipStream_t stream) {
    const float* s  = (const float*)d_in[0];
    const float* w1 = (const float*)d_in[1];
    const float* w2 = (const float*)d_in[2];
    const float* w3 = (const float*)d_in[3];
    const float* w4 = (const float*)d_in[4];
    float* out = (float*)d_out;

    const int Hd = 512, Wd = 512;
    const int planes = in_sizes[0] / (Hd * Wd);   // B*C = 192

    GaussCoefs gc;
    fill_gauss(gc.g3, 3);
    fill_gauss(gc.g5, 5);
    fill_gauss(gc.g7, 7);

    dim3 grid(Wd / TILE_X, Hd / TILE_Y, planes);
    mgdf_kernel<<<grid, 256, 0, stream>>>(s, w1, w2, w3, w4, out, gc);
}